// Round 2
// baseline (230402.271 us; speedup 1.0000x reference)
//
#include <hip/hip_runtime.h>
#include <hip/hip_cooperative_groups.h>
#include <cstddef>

namespace cg = cooperative_groups;

#define B_   32
#define TE_  512
#define TD_  512
#define NM_  80
#define PRE_ 256
#define EH_  512
#define AH_  1024
#define AD_  128

__device__ __forceinline__ float sigf(float x) { return 1.0f / (1.0f + expf(-x)); }

// ---------------- prologue: weight packing (unchanged from R1, verified) ----------------
// WTA4 layout: [k4][rp][4] rp = j*4+g (g: 0=i,1=f,2=g,3=o), k = [wih(768) ; whh(1024)]
// WTD4 layout: same, k = [wih(1536) ; whh(1024)]
__global__ __launch_bounds__(256) void k_pack_big(
    const float* __restrict__ a_wih, const float* __restrict__ a_whh,
    const float* __restrict__ d_wih, const float* __restrict__ d_whh,
    float* __restrict__ wta4, float* __restrict__ wtd4)
{
  int gid = blockIdx.x * 256 + threadIdx.x;
  const int NA = 448 * 4096;
  const int ND = 640 * 4096;
  if (gid < NA) {
    int k4 = gid >> 12, rp = gid & 4095;
    int j = rp >> 2, g = rp & 3, row = g * 1024 + j;
    int k = k4 * 4;
    float4 v;
    if (k < 768) v = *(const float4*)(a_wih + (size_t)row * 768 + k);
    else         v = *(const float4*)(a_whh + (size_t)row * 1024 + (k - 768));
    *(float4*)(wta4 + (size_t)gid * 4) = v;
  } else if (gid < NA + ND) {
    int g2 = gid - NA;
    int k4 = g2 >> 12, rp = g2 & 4095;
    int j = rp >> 2, g = rp & 3, row = g * 1024 + j;
    int k = k4 * 4;
    float4 v;
    if (k < 1536) v = *(const float4*)(d_wih + (size_t)row * 1536 + k);
    else          v = *(const float4*)(d_whh + (size_t)row * 1024 + (k - 1536));
    *(float4*)(wtd4 + (size_t)g2 * 4) = v;
  }
}

__global__ __launch_bounds__(256) void k_pack_small(
    const float* __restrict__ w1, const float* __restrict__ w2,
    const float* __restrict__ mw, const float* __restrict__ pw,
    const float* __restrict__ abih, const float* __restrict__ abhh,
    const float* __restrict__ dbih, const float* __restrict__ dbhh,
    const float* __restrict__ lw, const float* __restrict__ cw,
    float* __restrict__ w1t, float* __restrict__ w2t, float* __restrict__ mt,
    float* __restrict__ pjt, float* __restrict__ ba, float* __restrict__ bd,
    float* __restrict__ lc)
{
  int gid = blockIdx.x * 256 + threadIdx.x;
  if (gid < 20480) { int k = gid / 256, j = gid % 256; w1t[gid] = w1[j * 80 + k]; return; }
  gid -= 20480;
  if (gid < 65536) { int k = gid / 256, j = gid % 256; w2t[gid] = w2[j * 256 + k]; return; }
  gid -= 65536;
  if (gid < 65536) { int e = gid / 128, d = gid % 128; mt[gid] = mw[d * 512 + e]; return; }
  gid -= 65536;
  if (gid < 122880) { int k = gid / 80, m = gid % 80; pjt[gid] = pw[m * 1536 + k]; return; }
  gid -= 122880;
  if (gid < 4096) { int j = gid >> 2, g = gid & 3, row = g * 1024 + j; ba[gid] = abih[row] + abhh[row]; return; }
  gid -= 4096;
  if (gid < 4096) { int j = gid >> 2, g = gid & 3, row = g * 1024 + j; bd[gid] = dbih[row] + dbhh[row]; return; }
  gid -= 4096;
  if (gid < 7936) {
    int c = gid / (31 * 128), rem = gid % (31 * 128);
    int kk = rem / 128, d = rem % 128;
    float s = 0.f;
    for (int f = 0; f < 32; ++f) s += lw[d * 32 + f] * cw[(f * 2 + c) * 31 + kk];
    lc[gid] = s;
  }
}

// ---------------- prologue: prenet (unchanged) ----------------
__global__ __launch_bounds__(256) void k_prenet(
    const float* __restrict__ targets, const float* __restrict__ w1t,
    const float* __restrict__ b1, const float* __restrict__ w2t,
    const float* __restrict__ b2, float* __restrict__ pn)
{
  int t = blockIdx.x, tid = threadIdx.x;
  __shared__ float X[32][80];
  __shared__ float h1[256][33];
  for (int i = tid; i < 2560; i += 256) {
    int b = i / 80, m = i % 80;
    X[b][m] = (t == 0) ? 0.f : targets[((size_t)b * TD_ + (t - 1)) * NM_ + m];
  }
  __syncthreads();
  int j = tid;
  float bj = b1[j];
  for (int bt = 0; bt < 4; ++bt) {
    float acc[8];
#pragma unroll
    for (int i = 0; i < 8; ++i) acc[i] = bj;
    for (int k = 0; k < 80; ++k) {
      float w = w1t[k * 256 + j];
#pragma unroll
      for (int i = 0; i < 8; ++i) acc[i] += w * X[bt * 8 + i][k];
    }
#pragma unroll
    for (int i = 0; i < 8; ++i) h1[j][bt * 8 + i] = fmaxf(acc[i], 0.f);
  }
  __syncthreads();
  float cj = b2[j];
  float* out = pn + (size_t)t * PRE_ * B_;
  for (int bt = 0; bt < 4; ++bt) {
    float acc[8];
#pragma unroll
    for (int i = 0; i < 8; ++i) acc[i] = cj;
    for (int k = 0; k < 256; ++k) {
      float w = w2t[k * 256 + j];
#pragma unroll
      for (int i = 0; i < 8; ++i) acc[i] += w * h1[k][bt * 8 + i];
    }
#pragma unroll
    for (int i = 0; i < 8; ++i) out[j * 32 + bt * 8 + i] = fmaxf(acc[i], 0.f);
  }
}

// ---------------- prologue: processed_enc (unchanged) ----------------
__global__ __launch_bounds__(256) void k_penc(
    const float* __restrict__ enc, const float* __restrict__ mt,
    float* __restrict__ penc)
{
  int t = blockIdx.x, tid = threadIdx.x;
  __shared__ float encL[32][256];
  __shared__ float red[128][8][2];
  int d = tid & 127, s = tid >> 7;
  float acc[4][8];
#pragma unroll
  for (int bt = 0; bt < 4; ++bt)
#pragma unroll
    for (int i = 0; i < 8; ++i) acc[bt][i] = 0.f;
  for (int eh = 0; eh < 2; ++eh) {
    for (int i = tid; i < 8192; i += 256) {
      int b = i >> 8, e = i & 255;
      encL[b][e] = enc[((size_t)b * TE_ + t) * EH_ + eh * 256 + e];
    }
    __syncthreads();
    for (int bt = 0; bt < 4; ++bt) {
      for (int el = s * 128; el < s * 128 + 128; ++el) {
        float w = mt[(eh * 256 + el) * 128 + d];
#pragma unroll
        for (int i = 0; i < 8; ++i) acc[bt][i] += w * encL[bt * 8 + i][el];
      }
    }
    __syncthreads();
  }
  for (int bt = 0; bt < 4; ++bt) {
#pragma unroll
    for (int i = 0; i < 8; ++i) red[d][i][s] = acc[bt][i];
    __syncthreads();
    if (s == 0) {
#pragma unroll
      for (int i = 0; i < 8; ++i)
        penc[((size_t)t * AD_ + d) * 32 + bt * 8 + i] = red[d][i][0] + red[d][i][1];
    }
    __syncthreads();
  }
}

// ---------------- persistent step kernel ----------------
struct KP {
  const float* wta4; const float* wtd4; const float* pn; const float* penc;
  const float* qw;   const float* ww;   const float* pjt; const float* pjb;
  const float* lc;   const float* ba;   const float* bd;  const float* enc;
  float* ah; float* ac; float* dh; float* dc; float* ctx2; float* aw; float* aws;
  float* aht; float* enp; float* mel; float* align;
};

// one LSTM gate-block: 32 gate-rows (8 j), all 32 b, K split 4 ways
__device__ __forceinline__ void lstm_block(
    const float* __restrict__ wt4, int nk4, int rp0,
    const float* __restrict__ x0, int lim1,
    const float* __restrict__ x1, int off1, int lim2,
    const float* __restrict__ x2, int off2,
    const float* __restrict__ bias, float* __restrict__ cst,
    float* __restrict__ hout, float* __restrict__ aht,
    float* S, int tid)
{
  int rl = tid & 31, bq = (tid >> 5) & 3, ks = tid >> 7;
  int b0 = bq * 8;
  int per = nk4 >> 2;
  float4 a0 = {0, 0, 0, 0}, a1 = {0, 0, 0, 0};
  for (int k4 = ks * per; k4 < ks * per + per; ++k4) {
    float4 w4 = *(const float4*)(wt4 + ((size_t)k4 * 4096 + rp0 + rl) * 4);
    const float* xr;
    if (k4 < lim1)      xr = x0 + k4 * 128;
    else if (k4 < lim2) xr = x1 + (k4 * 4 - off1) * 32;
    else                xr = x2 + (k4 * 4 - off2) * 32;
#pragma unroll
    for (int e = 0; e < 4; ++e) {
      float we = (e == 0) ? w4.x : (e == 1) ? w4.y : (e == 2) ? w4.z : w4.w;
      float4 xa = *(const float4*)(xr + e * 32 + b0);
      float4 xb = *(const float4*)(xr + e * 32 + b0 + 4);
      a0.x += we * xa.x; a0.y += we * xa.y; a0.z += we * xa.z; a0.w += we * xa.w;
      a1.x += we * xb.x; a1.y += we * xb.y; a1.z += we * xb.z; a1.w += we * xb.w;
    }
  }
  float* red = S;                 // [4][32][33]
  float* gbuf = S + 4224;         // [32][33]
  int rb = (ks * 32 + rl) * 33 + b0;
  red[rb + 0] = a0.x; red[rb + 1] = a0.y; red[rb + 2] = a0.z; red[rb + 3] = a0.w;
  red[rb + 4] = a1.x; red[rb + 5] = a1.y; red[rb + 6] = a1.z; red[rb + 7] = a1.w;
  __syncthreads();
  {
    int o = tid, r2 = o & 31, b2 = o >> 5;
    gbuf[r2 * 33 + b2] = red[r2 * 33 + b2] + red[(32 + r2) * 33 + b2] +
                         red[(64 + r2) * 33 + b2] + red[(96 + r2) * 33 + b2];
    o = tid + 512; r2 = o & 31; b2 = o >> 5;
    gbuf[r2 * 33 + b2] = red[r2 * 33 + b2] + red[(32 + r2) * 33 + b2] +
                         red[(64 + r2) * 33 + b2] + red[(96 + r2) * 33 + b2];
  }
  __syncthreads();
  if (tid < 256) {
    int jl = tid & 7, bb = tid >> 3;
    float gi = gbuf[(jl * 4 + 0) * 33 + bb] + bias[rp0 + jl * 4 + 0];
    float gf = gbuf[(jl * 4 + 1) * 33 + bb] + bias[rp0 + jl * 4 + 1];
    float gg = gbuf[(jl * 4 + 2) * 33 + bb] + bias[rp0 + jl * 4 + 2];
    float go = gbuf[(jl * 4 + 3) * 33 + bb] + bias[rp0 + jl * 4 + 3];
    int j = (rp0 >> 2) + jl;
    float c0 = cst[j * 32 + bb];
    float c2 = sigf(gf) * c0 + sigf(gi) * tanhf(gg);
    float h2 = sigf(go) * tanhf(c2);
    cst[j * 32 + bb] = c2;
    hout[j * 32 + bb] = h2;
    if (aht) aht[(size_t)bb * 1024 + j] = h2;
  }
}

__device__ __forceinline__ void mel_block(
    const float* __restrict__ dhp, const float* __restrict__ ctp,
    const float* __restrict__ pjt, const float* __restrict__ pjb,
    float* __restrict__ mel, int bb, int tt, float* S, int tid)
{
  float* xo = S + 1536;   // 1536
  float* ro = S + 3072;   // 640
  for (int i = tid; i < 1536; i += 512)
    xo[i] = (i < 1024) ? dhp[i * 32 + bb] : ctp[(i - 1024) * 32 + bb];
  __syncthreads();
  if (tid < 480) {
    int m = tid % 80, k2 = tid / 80;
    float a2 = 0.f;
    for (int k = k2 * 256; k < k2 * 256 + 256; ++k) a2 += pjt[k * 80 + m] * xo[k];
    ro[m * 8 + k2] = a2;
  }
  __syncthreads();
  if (tid < 80) {
    float s3 = pjb[tid];
#pragma unroll
    for (int k = 0; k < 6; ++k) s3 += ro[tid * 8 + k];
    mel[((size_t)bb * TD_ + tt) * NM_ + tid] = s3;
  }
}

__global__ __launch_bounds__(512, 2) void k_step(KP p)
{
  cg::grid_group grid = cg::this_grid();
  __shared__ __align__(16) float S[5504];
  const int blk = blockIdx.x, tid = threadIdx.x;

  for (int t = 0; t < TD_; ++t) {
    const int pc = t & 1, pp = pc ^ 1;
    // ---- PA: lstm_a(t) [blocks 0..127] || lstm_d(t-1) [blocks 128..255] ----
    if (blk < 128) {
      lstm_block(p.wta4, 448, blk * 32,
                 p.pn + (size_t)t * 8192, 64,
                 p.ctx2 + pp * 16384, 256, 192,
                 p.ah + pp * 32768, 768,
                 p.ba, p.ac, p.ah + pc * 32768, p.aht, S, tid);
    } else if (t > 0) {
      lstm_block(p.wtd4, 640, (blk - 128) * 32,
                 p.ah + pp * 32768, 256,
                 p.ctx2 + pp * 16384, 1024, 384,
                 p.dh + pc * 32768, 1536,
                 p.bd, p.dc, p.dh + pp * 32768, nullptr, S, tid);
    }
    grid.sync();
    // ---- PB: q-slice + location conv + energies partials (all 256 blocks) ----
    {
      int tc = blk >> 3, ds = blk & 7;
      int t0 = tc * 16, d0 = ds * 16;
      float* win = S;          // [2][46][32]
      float* lcs = S + 2944;   // [2][31][16]
      float* qs  = S + 3936;   // [16][32]
      float* wws = S + 4448;   // [16]
      for (int i = tid; i < 2944; i += 512) {
        int c = i / 1472, r = (i >> 5) % 46, bb = i & 31;
        int tg = t0 - 15 + r;
        float v = 0.f;
        if (tg >= 0 && tg < 512) v = (c ? p.aws : p.aw)[tg * 32 + bb];
        win[i] = v;
      }
      for (int i = tid; i < 992; i += 512) {
        int c = i / 496, kk = (i >> 4) % 31, dl = i & 15;
        lcs[i] = p.lc[(c * 31 + kk) * 128 + d0 + dl];
      }
      if (tid < 16) wws[tid] = p.ww[d0 + tid];
      {
        int dl = tid & 15, bb = tid >> 4;
        const float* qrow = p.qw + (size_t)(d0 + dl) * 1024;
        const float* arow = p.aht + (size_t)bb * 1024;
        float acc = 0.f;
#pragma unroll 4
        for (int k = 0; k < 1024; k += 4) {
          float4 qv = *(const float4*)(qrow + k);
          float4 av = *(const float4*)(arow + k);
          acc += qv.x * av.x + qv.y * av.y + qv.z * av.z + qv.w * av.w;
        }
        qs[dl * 32 + bb] = acc;
      }
      __syncthreads();
      {
        int bb = tid & 31, th = tid >> 5;
        int tt = t0 + th;
        float pa[16];
#pragma unroll
        for (int i = 0; i < 16; ++i) pa[i] = 0.f;
        for (int c = 0; c < 2; ++c) {
          for (int kk = 0; kk < 31; ++kk) {
            float wv = win[c * 1472 + (th + kk) * 32 + bb];
            const float4* lr = (const float4*)(lcs + c * 496 + kk * 16);
            float4 l0 = lr[0], l1 = lr[1], l2 = lr[2], l3 = lr[3];
            pa[0]  += l0.x * wv; pa[1]  += l0.y * wv; pa[2]  += l0.z * wv; pa[3]  += l0.w * wv;
            pa[4]  += l1.x * wv; pa[5]  += l1.y * wv; pa[6]  += l1.z * wv; pa[7]  += l1.w * wv;
            pa[8]  += l2.x * wv; pa[9]  += l2.y * wv; pa[10] += l2.z * wv; pa[11] += l2.w * wv;
            pa[12] += l3.x * wv; pa[13] += l3.y * wv; pa[14] += l3.z * wv; pa[15] += l3.w * wv;
          }
        }
        float ep = 0.f;
#pragma unroll
        for (int dl = 0; dl < 16; ++dl) {
          float v = qs[dl * 32 + bb] + p.penc[((size_t)tt * 128 + d0 + dl) * 32 + bb] + pa[dl];
          ep += wws[dl] * tanhf(v);
        }
        p.enp[(size_t)bb * 4096 + tt * 8 + ds] = ep;
      }
    }
    grid.sync();
    // ---- PC: softmax + ctx (+aw/aws/align, +mel(t-1)) ----
    {
      int bb = blk >> 3, et = blk & 7;
      float* Sr  = S;          // 512
      float* awL = S + 512;    // 512
      float* cr  = S + 1024;   // 512
      const float4* ep4 = (const float4*)(p.enp + (size_t)bb * 4096 + tid * 8);
      float4 u0 = ep4[0], u1 = ep4[1];
      float e = u0.x + u0.y + u0.z + u0.w + u1.x + u1.y + u1.z + u1.w;
      Sr[tid] = e; __syncthreads();
      for (int off = 256; off; off >>= 1) {
        if (tid < off) Sr[tid] = fmaxf(Sr[tid], Sr[tid + off]);
        __syncthreads();
      }
      float mx = Sr[0]; __syncthreads();
      float x = expf(e - mx);
      Sr[tid] = x; __syncthreads();
      for (int off = 256; off; off >>= 1) {
        if (tid < off) Sr[tid] += Sr[tid + off];
        __syncthreads();
      }
      float a = x * (1.f / Sr[0]);
      awL[tid] = a;
      __syncthreads();
      int el = tid & 63, ts = tid >> 6;
      const float* eb = p.enc + (size_t)bb * 262144 + (size_t)ts * 64 * 512 + et * 64 + el;
      float acc = 0.f;
      for (int i = 0; i < 64; ++i) acc += awL[ts * 64 + i] * eb[(size_t)i * 512];
      cr[ts * 64 + el] = acc;
      __syncthreads();
      if (tid < 64) {
        float s2 = 0.f;
#pragma unroll
        for (int k = 0; k < 8; ++k) s2 += cr[k * 64 + tid];
        p.ctx2[pc * 16384 + (et * 64 + tid) * 32 + bb] = s2;
      }
      if (et == 0) {
        p.aw[tid * 32 + bb] = a;
        p.aws[tid * 32 + bb] += a;
        p.align[((size_t)bb * TD_ + t) * TE_ + tid] = a;
      }
      if (et == 1 && t > 0) {
        mel_block(p.dh + pp * 32768, p.ctx2 + pp * 16384, p.pjt, p.pjb,
                  p.mel, bb, t - 1, S, tid);
      }
    }
    grid.sync();
  }
  // ---- epilogue: lstm_d(511), then mel(511) ----
  if (blk >= 128) {
    // t == 512: pc = 0, pp = 1
    lstm_block(p.wtd4, 640, (blk - 128) * 32,
               p.ah + 32768, 256,
               p.ctx2 + 16384, 1024, 384,
               p.dh + 0, 1536,
               p.bd, p.dc, p.dh + 32768, nullptr, S, tid);
  }
  grid.sync();
  if (blk < 32) {
    mel_block(p.dh + 32768, p.ctx2 + 16384, p.pjt, p.pjb, p.mel, blk, 511, S, tid);
  }
}

extern "C" void kernel_launch(void* const* d_in, const int* in_sizes, int n_in,
                              void* d_out, int out_size, void* d_ws, size_t ws_size,
                              hipStream_t stream)
{
  const float* enc     = (const float*)d_in[0];
  const float* targets = (const float*)d_in[1];
  const float* pw1  = (const float*)d_in[2];
  const float* pb1  = (const float*)d_in[3];
  const float* pw2  = (const float*)d_in[4];
  const float* pb2  = (const float*)d_in[5];
  const float* mw   = (const float*)d_in[6];
  const float* qw   = (const float*)d_in[7];
  const float* www  = (const float*)d_in[8];
  const float* lw   = (const float*)d_in[9];
  const float* cw   = (const float*)d_in[10];
  const float* awih = (const float*)d_in[11];
  const float* awhh = (const float*)d_in[12];
  const float* abih = (const float*)d_in[13];
  const float* abhh = (const float*)d_in[14];
  const float* dwih = (const float*)d_in[15];
  const float* dwhh = (const float*)d_in[16];
  const float* dbih = (const float*)d_in[17];
  const float* dbhh = (const float*)d_in[18];
  const float* pjw  = (const float*)d_in[19];
  const float* pjb  = (const float*)d_in[20];

  float* ws = (float*)d_ws;
  float* WTA4 = ws;                        // 7,340,032
  float* WTD4 = WTA4 + 7340032;            // 10,485,760
  float* PN   = WTD4 + 10485760;           // 4,194,304
  float* PENC = PN + 4194304;              // 2,097,152
  float* W1T  = PENC + 2097152;            // 20,480  (prologue-only; ENP aliases here)
  float* W2T  = W1T + 20480;               // 65,536
  float* MT   = W2T + 65536;               // 65,536
  float* PJT  = MT + 65536;                // 122,880
  float* LC   = PJT + 122880;              // 7,936
  float* BA   = LC + 7936;                 // 4,096
  float* BD   = BA + 4096;                 // 4,096
  float* STATE = BD + 4096;                // 262,144 contiguous (memset once)
  float* AHb  = STATE;                     // 65,536 (2 parities)
  float* ACb  = AHb + 65536;               // 32,768
  float* DHb  = ACb + 32768;               // 65,536 (2 parities)
  float* DCb  = DHb + 65536;               // 32,768
  float* CTXb = DCb + 32768;               // 32,768 (2 parities)
  float* AWb  = CTXb + 32768;              // 16,384
  float* AWSb = AWb + 16384;               // 16,384
  float* AHT  = STATE + 262144;            // 32,768
  float* ENP  = W1T;                       // alias: 131,072 <= 151,552 (W1T+W2T+MT)

  hipMemsetAsync(STATE, 0, (size_t)262144 * sizeof(float), stream);

  float* mel = (float*)d_out;
  float* align = mel + (size_t)B_ * TD_ * NM_;

  k_pack_big<<<17408, 256, 0, stream>>>(awih, awhh, dwih, dwhh, WTA4, WTD4);
  k_pack_small<<<1135, 256, 0, stream>>>(pw1, pw2, mw, pjw, abih, abhh, dbih, dbhh,
                                         lw, cw, W1T, W2T, MT, PJT, BA, BD, LC);
  k_prenet<<<512, 256, 0, stream>>>(targets, W1T, pb1, W2T, pb2, PN);
  k_penc<<<512, 256, 0, stream>>>(enc, MT, PENC);

  KP kp;
  kp.wta4 = WTA4; kp.wtd4 = WTD4; kp.pn = PN; kp.penc = PENC;
  kp.qw = qw; kp.ww = www; kp.pjt = PJT; kp.pjb = pjb;
  kp.lc = LC; kp.ba = BA; kp.bd = BD; kp.enc = enc;
  kp.ah = AHb; kp.ac = ACb; kp.dh = DHb; kp.dc = DCb;
  kp.ctx2 = CTXb; kp.aw = AWb; kp.aws = AWSb;
  kp.aht = AHT; kp.enp = ENP; kp.mel = mel; kp.align = align;

  void* kargs[] = { &kp };
  hipLaunchCooperativeKernel((const void*)k_step, dim3(256), dim3(512), kargs, 0, stream);
}